// Round 4
// baseline (610.306 us; speedup 1.0000x reference)
//
#include <hip/hip_runtime.h>
#include <hip/hip_bf16.h>
#include <cstdint>

// Problem constants (from reference): B,T,E,C,I_E,O = 4,2048,8,512,512,4096
constexpr int NB = 4;
constexpr int NT = 2048;
constexpr int NE = 8;
constexpr int NC = 512;
constexpr int NI = 512;
constexpr int NO = 4096;
constexpr int NEC = NE * NC;  // 4096 (stage-2 K)

typedef __attribute__((ext_vector_type(8))) short short8;
typedef __attribute__((ext_vector_type(8))) unsigned short ushort8;
typedef __attribute__((ext_vector_type(4))) float f32x4;

// f32 -> bf16 round-to-nearest-even (inputs are finite; no NaN path needed)
__device__ __forceinline__ unsigned short f2bf(float f) {
  unsigned int u = __builtin_bit_cast(unsigned int, f);
  u += 0x7FFFu + ((u >> 16) & 1u);
  return (unsigned short)(u >> 16);
}

__device__ __forceinline__ ushort8 cvt8(float4 a, float4 b) {
  ushort8 v;
  v[0] = f2bf(a.x); v[1] = f2bf(a.y); v[2] = f2bf(a.z); v[3] = f2bf(a.w);
  v[4] = f2bf(b.x); v[5] = f2bf(b.y); v[6] = f2bf(b.z); v[7] = f2bf(b.w);
  return v;
}

// LDS tile is [128 rows][32 bf16] = row stride 64 B. XOR-swizzle bits 4-5 with
// row bits 1-2 so the 16-lane b128 fragment reads (rows r..r+15, fixed kbyte)
// land on 8 distinct 16B slots per 128B window -> 2-way (free) conflicts.
__device__ __forceinline__ int lds_byte(int row, int kbyte) {
  return (row * 64 + kbyte) ^ ((row & 6) << 3);
}

// ---------------------------------------------------------------------------
// Stage 1: eoT[b][o][e][c] = sum_i W[e,o,i] * x[b,e,c,i] + bias[o]   (bf16 out)
// A-operand = W[e] (M = O, K-major), B-operand = x[b,e] (N = C, K-major).
// Tile 128x128, BK=32, 4 waves, each wave = 64x64 (4x4 frags of 16x16x32).
// ---------------------------------------------------------------------------
__global__ __launch_bounds__(256, 2) void k_gemm1(
    const float* __restrict__ x, const float* __restrict__ W,
    const float* __restrict__ bias, unsigned short* __restrict__ eoT) {
  const int tile = blockIdx.x;           // 32 o-tiles x 4 c-tiles = 128
  const int e = blockIdx.y, b = blockIdx.z;
  const int bm = tile >> 2, bn = tile & 3;
  const int tid = threadIdx.x, lane = tid & 63, wv = tid >> 6;
  const int wr = wv >> 1, wc = wv & 1;

  const float* Ag = W + (size_t)e * NO * NI + (size_t)(bm * 128) * NI;
  const float* Bg = x + ((size_t)b * NE + e) * NC * NI + (size_t)(bn * 128) * NI;

  __shared__ __align__(16) unsigned short As[128 * 32];
  __shared__ __align__(16) unsigned short Bs[128 * 32];

  f32x4 acc[4][4];
#pragma unroll
  for (int m = 0; m < 4; ++m)
#pragma unroll
    for (int n = 0; n < 4; ++n) acc[m][n] = (f32x4)0.f;

  for (int k0 = 0; k0 < NI; k0 += 32) {
    __syncthreads();
    // stage: 128x32 f32 -> bf16 for A and B; 512 8-elem chunks each
#pragma unroll
    for (int s = 0; s < 2; ++s) {
      const int q = tid + s * 256;
      const int row = q >> 2, kc = (q & 3) * 8;
      const float* ga = Ag + (size_t)row * NI + k0 + kc;
      float4 a0 = *(const float4*)ga;
      float4 a1 = *(const float4*)(ga + 4);
      *(ushort8*)((char*)As + lds_byte(row, kc * 2)) = cvt8(a0, a1);
      const float* gb = Bg + (size_t)row * NI + k0 + kc;
      float4 b0 = *(const float4*)gb;
      float4 b1 = *(const float4*)(gb + 4);
      *(ushort8*)((char*)Bs + lds_byte(row, kc * 2)) = cvt8(b0, b1);
    }
    __syncthreads();

    const int kb = (lane >> 4) * 16;   // 16B = this lane's 8 K-elems
    short8 af[4], bfv[4];
#pragma unroll
    for (int m = 0; m < 4; ++m) {
      const int r = wr * 64 + m * 16 + (lane & 15);
      af[m] = *(const short8*)((const char*)As + lds_byte(r, kb));
    }
#pragma unroll
    for (int n = 0; n < 4; ++n) {
      const int r = wc * 64 + n * 16 + (lane & 15);
      bfv[n] = *(const short8*)((const char*)Bs + lds_byte(r, kb));
    }
#pragma unroll
    for (int m = 0; m < 4; ++m)
#pragma unroll
      for (int n = 0; n < 4; ++n)
        acc[m][n] = __builtin_amdgcn_mfma_f32_16x16x32_bf16(
            af[m], bfv[n], acc[m][n], 0, 0, 0);
  }

  // Epilogue: D[o_local, c_local]; C/D layout col=lane&15 (c), row=(lane>>4)*4+j (o)
  const int o0 = bm * 128 + wr * 64;
  const int c0 = bn * 128 + wc * 64;
#pragma unroll
  for (int m = 0; m < 4; ++m) {
#pragma unroll
    for (int j = 0; j < 4; ++j) {
      const int o = o0 + m * 16 + (lane >> 4) * 4 + j;
      const float bv = bias[o];
      const size_t base = (((size_t)b * NO + o) * NE + e) * NC + c0;
#pragma unroll
      for (int n = 0; n < 4; ++n) {
        const int c = n * 16 + (lane & 15);
        eoT[base + c] = f2bf(acc[m][n][j] + bv);
      }
    }
  }
}

// ---------------------------------------------------------------------------
// Stage 2: out[b,t,o] = sum_{k=(e,c)} combine[b,t,e,c] * eoT[b,o,e,c]
// A-operand = combine[b] (M = T, K=EC, K-major, f32->bf16 reg-staged)
// B-operand = eoT[b]     (N = O, K=EC, K-major, already bf16)
// ---------------------------------------------------------------------------
__global__ __launch_bounds__(256, 2) void k_gemm2(
    const float* __restrict__ comb, const unsigned short* __restrict__ eoT,
    float* __restrict__ out) {
  const int b = blockIdx.y;
  const int bm = blockIdx.x >> 5;   // t-tile 0..15
  const int bn = blockIdx.x & 31;   // o-tile 0..31 (fast dim -> A-tile L2 reuse)
  const int tid = threadIdx.x, lane = tid & 63, wv = tid >> 6;
  const int wr = wv >> 1, wc = wv & 1;

  const float* Ag = comb + (size_t)b * NT * NEC + (size_t)(bm * 128) * NEC;
  const unsigned short* Bg = eoT + (size_t)b * NO * NEC + (size_t)(bn * 128) * NEC;

  __shared__ __align__(16) unsigned short As[128 * 32];
  __shared__ __align__(16) unsigned short Bs[128 * 32];

  f32x4 acc[4][4];
#pragma unroll
  for (int m = 0; m < 4; ++m)
#pragma unroll
    for (int n = 0; n < 4; ++n) acc[m][n] = (f32x4)0.f;

  for (int k0 = 0; k0 < NEC; k0 += 32) {
    __syncthreads();
#pragma unroll
    for (int s = 0; s < 2; ++s) {
      const int q = tid + s * 256;
      const int row = q >> 2, kc = (q & 3) * 8;
      const float* ga = Ag + (size_t)row * NEC + k0 + kc;
      float4 a0 = *(const float4*)ga;
      float4 a1 = *(const float4*)(ga + 4);
      *(ushort8*)((char*)As + lds_byte(row, kc * 2)) = cvt8(a0, a1);
      // B is already bf16: straight 16B copy through regs
      ushort8 bv = *(const ushort8*)(Bg + (size_t)row * NEC + k0 + kc);
      *(ushort8*)((char*)Bs + lds_byte(row, kc * 2)) = bv;
    }
    __syncthreads();

    const int kb = (lane >> 4) * 16;
    short8 af[4], bfv[4];
#pragma unroll
    for (int m = 0; m < 4; ++m) {
      const int r = wr * 64 + m * 16 + (lane & 15);
      af[m] = *(const short8*)((const char*)As + lds_byte(r, kb));
    }
#pragma unroll
    for (int n = 0; n < 4; ++n) {
      const int r = wc * 64 + n * 16 + (lane & 15);
      bfv[n] = *(const short8*)((const char*)Bs + lds_byte(r, kb));
    }
#pragma unroll
    for (int m = 0; m < 4; ++m)
#pragma unroll
      for (int n = 0; n < 4; ++n)
        acc[m][n] = __builtin_amdgcn_mfma_f32_16x16x32_bf16(
            af[m], bfv[n], acc[m][n], 0, 0, 0);
  }

  // Epilogue: D[t_local, o_local]; col=lane&15 (o), row=(lane>>4)*4+j (t)
  const int t0 = bm * 128 + wr * 64;
  const int o0 = bn * 128 + wc * 64;
#pragma unroll
  for (int m = 0; m < 4; ++m) {
#pragma unroll
    for (int j = 0; j < 4; ++j) {
      const int t = t0 + m * 16 + (lane >> 4) * 4 + j;
      float* op = out + ((size_t)b * NT + t) * NO + o0;
#pragma unroll
      for (int n = 0; n < 4; ++n) {
        op[n * 16 + (lane & 15)] = acc[m][n][j];
      }
    }
  }
}

extern "C" void kernel_launch(void* const* d_in, const int* in_sizes, int n_in,
                              void* d_out, int out_size, void* d_ws, size_t ws_size,
                              hipStream_t stream) {
  const float* x    = (const float*)d_in[0];  // [B,E,C,I]
  const float* comb = (const float*)d_in[1];  // [B,T,E,C]
  const float* W    = (const float*)d_in[2];  // [E,O,I]
  const float* bias = (const float*)d_in[3];  // [O]
  float* out = (float*)d_out;                 // [B,T,O]

  // Workspace: eoT[b][o][e][c] bf16 = 4*4096*8*512*2 = 134,217,728 bytes
  unsigned short* eoT = (unsigned short*)d_ws;

  k_gemm1<<<dim3(128, NE, NB), 256, 0, stream>>>(x, W, bias, eoT);
  k_gemm2<<<dim3(512, NB), 256, 0, stream>>>(comb, eoT, out);
}